// Round 1
// baseline (1111.122 us; speedup 1.0000x reference)
//
#include <hip/hip_runtime.h>
#include <hip/hip_bf16.h>

// GCN layer: out = spmm(adj, x @ W) + bias
// Inputs: x[50000,128] f32, weight[128,128] f32, bias[128] f32,
//         edge_vals[625000] f32, edge_rows[625000] i32, edge_cols[625000] i32
// Output: out[50000,128] f32

#define F_DIM 128
#define ROWS_PER_BLOCK 16

// out[n][f] = bias[f]  (so the scatter-add can accumulate in place)
__global__ void init_out_kernel(float* __restrict__ out,
                                const float* __restrict__ bias, int total4) {
    int idx = blockIdx.x * blockDim.x + threadIdx.x;
    int stride = gridDim.x * blockDim.x;
    for (int i = idx; i < total4; i += stride) {
        // 128 floats per row, 32 float4 per row
        float4 b = *reinterpret_cast<const float4*>(bias + ((i & 31) << 2));
        reinterpret_cast<float4*>(out)[i] = b;
    }
}

// support = x @ W   (fp32 vector-ALU GEMM)
// block = 256 threads, computes 16 rows x 128 cols.
// Thread t: col = t & 127, rows r0..r0+7 where r0 = (t>>7)*8.
__global__ void __launch_bounds__(256)
gemm_kernel(const float* __restrict__ x, const float* __restrict__ w,
            float* __restrict__ support, int n_nodes) {
    __shared__ float xs[ROWS_PER_BLOCK][F_DIM];  // 8 KB

    const int tid = threadIdx.x;
    const int block_row = blockIdx.x * ROWS_PER_BLOCK;

    // Stage the 16x128 x-tile into LDS (float4 loads, coalesced).
    const float4* x4 = reinterpret_cast<const float4*>(x) + block_row * (F_DIM / 4);
    float4* xs4 = reinterpret_cast<float4*>(&xs[0][0]);
    for (int i = tid; i < ROWS_PER_BLOCK * (F_DIM / 4); i += 256) {
        int r = i >> 5;  // i / 32
        if (block_row + r < n_nodes) xs4[i] = x4[i];
    }
    __syncthreads();

    const int col = tid & 127;
    const int r0 = (tid >> 7) * 8;

    float acc[8];
#pragma unroll
    for (int j = 0; j < 8; j++) acc[j] = 0.0f;

    // k-loop in chunks of 4: wave-uniform ds_read_b128 of x (broadcast, free),
    // coalesced global loads of w column-slices (w is L2-resident, 64 KB).
    for (int k4 = 0; k4 < F_DIM / 4; k4++) {
        const int k = k4 * 4;
        float w0 = w[(k + 0) * F_DIM + col];
        float w1 = w[(k + 1) * F_DIM + col];
        float w2 = w[(k + 2) * F_DIM + col];
        float w3 = w[(k + 3) * F_DIM + col];
#pragma unroll
        for (int j = 0; j < 8; j++) {
            float4 xv = xs4[(r0 + j) * (F_DIM / 4) + k4];
            acc[j] += xv.x * w0;
            acc[j] += xv.y * w1;
            acc[j] += xv.z * w2;
            acc[j] += xv.w * w3;
        }
    }

#pragma unroll
    for (int j = 0; j < 8; j++) {
        int row = block_row + r0 + j;
        if (row < n_nodes) support[row * F_DIM + col] = acc[j];
    }
}

// Scatter: for each edge e: out[rows[e]] += vals[e] * support[cols[e]]
// 32 lanes per edge, float4 per lane (128 floats / edge).
__global__ void __launch_bounds__(256)
spmm_kernel(const float* __restrict__ support, const float* __restrict__ vals,
            const int* __restrict__ rows, const int* __restrict__ cols,
            float* __restrict__ out, int n_edges) {
    int gid = blockIdx.x * blockDim.x + threadIdx.x;
    int lane = gid & 31;
    int e = gid >> 5;
    int estride = (gridDim.x * blockDim.x) >> 5;

    for (; e < n_edges; e += estride) {
        int c = cols[e];
        int r = rows[e];
        float v = vals[e];
        float4 s = *reinterpret_cast<const float4*>(support + c * F_DIM + lane * 4);
        float* o = out + r * F_DIM + lane * 4;
        atomicAdd(o + 0, v * s.x);
        atomicAdd(o + 1, v * s.y);
        atomicAdd(o + 2, v * s.z);
        atomicAdd(o + 3, v * s.w);
    }
}

extern "C" void kernel_launch(void* const* d_in, const int* in_sizes, int n_in,
                              void* d_out, int out_size, void* d_ws, size_t ws_size,
                              hipStream_t stream) {
    const float* x      = (const float*)d_in[0];
    const float* weight = (const float*)d_in[1];
    const float* bias   = (const float*)d_in[2];
    const float* evals  = (const float*)d_in[3];
    const int*   erows  = (const int*)d_in[4];
    const int*   ecols  = (const int*)d_in[5];
    float* out = (float*)d_out;

    const int n_nodes = in_sizes[0] / F_DIM;   // 50000
    const int n_edges = in_sizes[3];           // 625000

    float* support = (float*)d_ws;             // n_nodes*128 floats = 25.6 MB

    // 1) out = bias (broadcast)
    init_out_kernel<<<2048, 256, 0, stream>>>(out, bias, out_size / 4);

    // 2) support = x @ W
    int gemm_blocks = (n_nodes + ROWS_PER_BLOCK - 1) / ROWS_PER_BLOCK;
    gemm_kernel<<<gemm_blocks, 256, 0, stream>>>(x, weight, support, n_nodes);

    // 3) out += scatter(edges, support)
    spmm_kernel<<<2048, 256, 0, stream>>>(support, evals, erows, ecols, out, n_edges);
}

// Round 2
// 299.544 us; speedup vs baseline: 3.7094x; 3.7094x over previous
//
#include <hip/hip_runtime.h>
#include <hip/hip_bf16.h>

// GCN layer: out = spmm(adj, x @ W) + bias
// Inputs: x[50000,128] f32, weight[128,128] f32, bias[128] f32,
//         edge_vals[625000] f32, edge_rows[625000] i32, edge_cols[625000] i32
// Output: out[50000,128] f32
//
// Strategy: counting-sort edges by row into CSR (on device, every call),
// then pull-style segment sum: one wave per row, no atomics on the output.

#define F_DIM 128
#define ROWS_PER_BLOCK 16

// ---------------- GEMM: support = x @ W (fp32 vector ALU) ----------------
__global__ void __launch_bounds__(256)
gemm_kernel(const float* __restrict__ x, const float* __restrict__ w,
            float* __restrict__ support, int n_nodes) {
    __shared__ float xs[ROWS_PER_BLOCK][F_DIM];  // 8 KB

    const int tid = threadIdx.x;
    const int block_row = blockIdx.x * ROWS_PER_BLOCK;

    const float4* x4 = reinterpret_cast<const float4*>(x) + block_row * (F_DIM / 4);
    float4* xs4 = reinterpret_cast<float4*>(&xs[0][0]);
    for (int i = tid; i < ROWS_PER_BLOCK * (F_DIM / 4); i += 256) {
        int r = i >> 5;
        if (block_row + r < n_nodes) xs4[i] = x4[i];
    }
    __syncthreads();

    const int col = tid & 127;
    const int r0 = (tid >> 7) * 8;

    float acc[8];
#pragma unroll
    for (int j = 0; j < 8; j++) acc[j] = 0.0f;

    for (int k4 = 0; k4 < F_DIM / 4; k4++) {
        const int k = k4 * 4;
        float w0 = w[(k + 0) * F_DIM + col];
        float w1 = w[(k + 1) * F_DIM + col];
        float w2 = w[(k + 2) * F_DIM + col];
        float w3 = w[(k + 3) * F_DIM + col];
#pragma unroll
        for (int j = 0; j < 8; j++) {
            float4 xv = xs4[(r0 + j) * (F_DIM / 4) + k4];
            acc[j] += xv.x * w0;
            acc[j] += xv.y * w1;
            acc[j] += xv.z * w2;
            acc[j] += xv.w * w3;
        }
    }

#pragma unroll
    for (int j = 0; j < 8; j++) {
        int row = block_row + r0 + j;
        if (row < n_nodes) support[row * F_DIM + col] = acc[j];
    }
}

// ---------------- Counting sort: histogram ----------------
__global__ void hist_kernel(const int* __restrict__ rows, int* __restrict__ cnt,
                            int n_edges) {
    int idx = blockIdx.x * blockDim.x + threadIdx.x;
    int stride = gridDim.x * blockDim.x;
    for (int e = idx; e < n_edges; e += stride)
        atomicAdd(&cnt[rows[e]], 1);
}

// ---------------- Counting sort: single-block exclusive scan ----------------
__global__ void __launch_bounds__(1024)
scan_kernel(const int* __restrict__ cnt, int* __restrict__ off,
            int* __restrict__ cur, int n) {
    __shared__ int partial[1024];
    const int t = threadIdx.x;
    const int chunk = (n + 1023) >> 10;
    const int s = t * chunk;
    const int e = min(s + chunk, n);

    int sum = 0;
    for (int i = s; i < e; i++) sum += cnt[i];
    partial[t] = sum;
    __syncthreads();

    // Hillis-Steele inclusive scan over the 1024 partials
    for (int d = 1; d < 1024; d <<= 1) {
        int v = (t >= d) ? partial[t - d] : 0;
        __syncthreads();
        partial[t] += v;
        __syncthreads();
    }

    int run = (t == 0) ? 0 : partial[t - 1];
    for (int i = s; i < e; i++) {
        off[i] = run;
        cur[i] = run;
        run += cnt[i];
    }
    if (t == 1023) off[n] = run;  // run == grand total here (empty slice ok)
}

// ---------------- Counting sort: scatter edges into CSR order ----------------
__global__ void scatter_kernel(const int* __restrict__ rows,
                               const int* __restrict__ cols,
                               const float* __restrict__ vals,
                               int* __restrict__ cur,
                               int* __restrict__ scol, float* __restrict__ sval,
                               int n_edges) {
    int idx = blockIdx.x * blockDim.x + threadIdx.x;
    int stride = gridDim.x * blockDim.x;
    for (int e = idx; e < n_edges; e += stride) {
        int pos = atomicAdd(&cur[rows[e]], 1);
        scol[pos] = cols[e];
        sval[pos] = vals[e];
    }
}

// ---------------- SpMM over CSR: one wave per row, no atomics ----------------
__global__ void __launch_bounds__(256)
spmm_csr_kernel(const float* __restrict__ support, const int* __restrict__ off,
                const int* __restrict__ scol, const float* __restrict__ sval,
                const float* __restrict__ bias, float* __restrict__ out,
                int n_nodes) {
    const int wave = (blockIdx.x * blockDim.x + threadIdx.x) >> 6;
    const int lane = threadIdx.x & 63;
    if (wave >= n_nodes) return;

    const int r = wave;
    const int s = off[r];
    const int e = off[r + 1];

    float2 acc = make_float2(0.0f, 0.0f);
    for (int i = s; i < e; i++) {
        int c = scol[i];
        float v = sval[i];
        float2 sv = *reinterpret_cast<const float2*>(support + c * F_DIM + lane * 2);
        acc.x += v * sv.x;
        acc.y += v * sv.y;
    }
    float2 b = *reinterpret_cast<const float2*>(bias + lane * 2);
    float2 o = make_float2(acc.x + b.x, acc.y + b.y);
    *reinterpret_cast<float2*>(out + r * F_DIM + lane * 2) = o;
}

extern "C" void kernel_launch(void* const* d_in, const int* in_sizes, int n_in,
                              void* d_out, int out_size, void* d_ws, size_t ws_size,
                              hipStream_t stream) {
    const float* x      = (const float*)d_in[0];
    const float* weight = (const float*)d_in[1];
    const float* bias   = (const float*)d_in[2];
    const float* evals  = (const float*)d_in[3];
    const int*   erows  = (const int*)d_in[4];
    const int*   ecols  = (const int*)d_in[5];
    float* out = (float*)d_out;

    const int n_nodes = in_sizes[0] / F_DIM;   // 50000
    const int n_edges = in_sizes[3];           // 625000

    // Workspace layout (~31.2 MB)
    float* support = (float*)d_ws;                       // n_nodes*128 f32
    int*   cnt     = (int*)(support + (size_t)n_nodes * F_DIM);  // n_nodes
    int*   off     = cnt + n_nodes;                      // n_nodes+1
    int*   cur     = off + n_nodes + 1;                  // n_nodes
    int*   scol    = cur + n_nodes;                      // n_edges
    float* sval    = (float*)(scol + n_edges);           // n_edges

    // 1) zero the histogram
    hipMemsetAsync(cnt, 0, n_nodes * sizeof(int), stream);

    // 2) support = x @ W
    int gemm_blocks = (n_nodes + ROWS_PER_BLOCK - 1) / ROWS_PER_BLOCK;
    gemm_kernel<<<gemm_blocks, 256, 0, stream>>>(x, weight, support, n_nodes);

    // 3) counting sort by row
    hist_kernel<<<1024, 256, 0, stream>>>(erows, cnt, n_edges);
    scan_kernel<<<1, 1024, 0, stream>>>(cnt, off, cur, n_nodes);
    scatter_kernel<<<1024, 256, 0, stream>>>(erows, ecols, evals, cur, scol, sval, n_edges);

    // 4) out[r] = sum_e v*support[col] + bias   (wave per row, no atomics)
    int waves = n_nodes;
    int blocks = (waves * 64 + 255) / 256;
    spmm_csr_kernel<<<blocks, 256, 0, stream>>>(support, off, scol, sval, bias, out, n_nodes);
}

// Round 3
// 205.620 us; speedup vs baseline: 5.4038x; 1.4568x over previous
//
#include <hip/hip_runtime.h>
#include <hip/hip_bf16.h>

// GCN layer: out = spmm(adj, x @ W) + bias
// Inputs: x[50000,128] f32, weight[128,128] f32, bias[128] f32,
//         edge_vals[625000] f32, edge_rows[625000] i32, edge_cols[625000] i32
// Output: out[50000,128] f32
//
// Strategy: counting-sort edges by row into CSR (device-side, every call),
// then pull-style segment sum: one wave per row, no atomics on the output.
// Scan is 3-phase multi-block (round-2 fix: single-block scan was 109 us
// at 0.14% occupancy).

#define F_DIM 128
#define ROWS_PER_BLOCK 16

#define SCAN_T 256
#define SCAN_ITEMS 4
#define SCAN_PER_BLOCK (SCAN_T * SCAN_ITEMS)   // 1024 elements per block

// ---------------- GEMM: support = x @ W (fp32 vector ALU) ----------------
__global__ void __launch_bounds__(256)
gemm_kernel(const float* __restrict__ x, const float* __restrict__ w,
            float* __restrict__ support, int n_nodes) {
    __shared__ float xs[ROWS_PER_BLOCK][F_DIM];  // 8 KB

    const int tid = threadIdx.x;
    const int block_row = blockIdx.x * ROWS_PER_BLOCK;

    const float4* x4 = reinterpret_cast<const float4*>(x) + block_row * (F_DIM / 4);
    float4* xs4 = reinterpret_cast<float4*>(&xs[0][0]);
    for (int i = tid; i < ROWS_PER_BLOCK * (F_DIM / 4); i += 256) {
        int r = i >> 5;
        if (block_row + r < n_nodes) xs4[i] = x4[i];
    }
    __syncthreads();

    const int col = tid & 127;
    const int r0 = (tid >> 7) * 8;

    float acc[8];
#pragma unroll
    for (int j = 0; j < 8; j++) acc[j] = 0.0f;

    for (int k4 = 0; k4 < F_DIM / 4; k4++) {
        const int k = k4 * 4;
        float w0 = w[(k + 0) * F_DIM + col];
        float w1 = w[(k + 1) * F_DIM + col];
        float w2 = w[(k + 2) * F_DIM + col];
        float w3 = w[(k + 3) * F_DIM + col];
#pragma unroll
        for (int j = 0; j < 8; j++) {
            float4 xv = xs4[(r0 + j) * (F_DIM / 4) + k4];
            acc[j] += xv.x * w0;
            acc[j] += xv.y * w1;
            acc[j] += xv.z * w2;
            acc[j] += xv.w * w3;
        }
    }

#pragma unroll
    for (int j = 0; j < 8; j++) {
        int row = block_row + r0 + j;
        if (row < n_nodes) support[row * F_DIM + col] = acc[j];
    }
}

// ---------------- Counting sort: histogram ----------------
__global__ void hist_kernel(const int* __restrict__ rows, int* __restrict__ cnt,
                            int n_edges) {
    int idx = blockIdx.x * blockDim.x + threadIdx.x;
    int stride = gridDim.x * blockDim.x;
    for (int e = idx; e < n_edges; e += stride)
        atomicAdd(&cnt[rows[e]], 1);
}

// ---------------- Scan phase 1: per-block sums ----------------
__global__ void __launch_bounds__(SCAN_T)
scan_phase1(const int* __restrict__ cnt, int* __restrict__ bsum, int n) {
    __shared__ int red[SCAN_T];
    const int t = threadIdx.x;
    const int base = blockIdx.x * SCAN_PER_BLOCK + t * SCAN_ITEMS;

    int s = 0;
#pragma unroll
    for (int j = 0; j < SCAN_ITEMS; j++) {
        int i = base + j;
        if (i < n) s += cnt[i];
    }
    red[t] = s;
    __syncthreads();
    for (int d = SCAN_T / 2; d > 0; d >>= 1) {
        if (t < d) red[t] += red[t + d];
        __syncthreads();
    }
    if (t == 0) bsum[blockIdx.x] = red[0];
}

// ---------------- Scan phase 2: scan the block sums (1 small block) -------
__global__ void __launch_bounds__(SCAN_T)
scan_phase2(const int* __restrict__ bsum, int* __restrict__ bbase,
            int* __restrict__ off, int nblocks, int n) {
    __shared__ int sh[SCAN_T];
    const int t = threadIdx.x;
    int v = (t < nblocks) ? bsum[t] : 0;
    sh[t] = v;
    __syncthreads();
    // Hillis-Steele inclusive scan
    for (int d = 1; d < SCAN_T; d <<= 1) {
        int u = (t >= d) ? sh[t - d] : 0;
        __syncthreads();
        sh[t] += u;
        __syncthreads();
    }
    if (t < nblocks) bbase[t] = (t == 0) ? 0 : sh[t - 1];
    if (t == 0) off[n] = sh[SCAN_T - 1];   // grand total (= n_edges)
}

// ---------------- Scan phase 3: emit per-element offsets ----------------
__global__ void __launch_bounds__(SCAN_T)
scan_phase3(const int* __restrict__ cnt, const int* __restrict__ bbase,
            int* __restrict__ off, int* __restrict__ cur, int n) {
    __shared__ int sh[SCAN_T];
    const int t = threadIdx.x;
    const int base = blockIdx.x * SCAN_PER_BLOCK + t * SCAN_ITEMS;

    int local[SCAN_ITEMS];
    int s = 0;
#pragma unroll
    for (int j = 0; j < SCAN_ITEMS; j++) {
        int i = base + j;
        local[j] = (i < n) ? cnt[i] : 0;
        s += local[j];
    }
    sh[t] = s;
    __syncthreads();
    // Hillis-Steele inclusive scan over thread sums
    for (int d = 1; d < SCAN_T; d <<= 1) {
        int u = (t >= d) ? sh[t - d] : 0;
        __syncthreads();
        sh[t] += u;
        __syncthreads();
    }
    int run = bbase[blockIdx.x] + ((t == 0) ? 0 : sh[t - 1]);
#pragma unroll
    for (int j = 0; j < SCAN_ITEMS; j++) {
        int i = base + j;
        if (i < n) {
            off[i] = run;
            cur[i] = run;
            run += local[j];
        }
    }
}

// ---------------- Counting sort: scatter edges into CSR order ----------------
__global__ void scatter_kernel(const int* __restrict__ rows,
                               const int* __restrict__ cols,
                               const float* __restrict__ vals,
                               int* __restrict__ cur,
                               int* __restrict__ scol, float* __restrict__ sval,
                               int n_edges) {
    int idx = blockIdx.x * blockDim.x + threadIdx.x;
    int stride = gridDim.x * blockDim.x;
    for (int e = idx; e < n_edges; e += stride) {
        int pos = atomicAdd(&cur[rows[e]], 1);
        scol[pos] = cols[e];
        sval[pos] = vals[e];
    }
}

// ---------------- SpMM over CSR: one wave per row, no atomics ----------------
__global__ void __launch_bounds__(256)
spmm_csr_kernel(const float* __restrict__ support, const int* __restrict__ off,
                const int* __restrict__ scol, const float* __restrict__ sval,
                const float* __restrict__ bias, float* __restrict__ out,
                int n_nodes) {
    const int wave = (blockIdx.x * blockDim.x + threadIdx.x) >> 6;
    const int lane = threadIdx.x & 63;
    if (wave >= n_nodes) return;

    const int r = wave;
    const int s = off[r];
    const int e = off[r + 1];

    float2 acc = make_float2(0.0f, 0.0f);
    for (int i = s; i < e; i++) {
        int c = scol[i];
        float v = sval[i];
        float2 sv = *reinterpret_cast<const float2*>(support + c * F_DIM + lane * 2);
        acc.x += v * sv.x;
        acc.y += v * sv.y;
    }
    float2 b = *reinterpret_cast<const float2*>(bias + lane * 2);
    float2 o = make_float2(acc.x + b.x, acc.y + b.y);
    *reinterpret_cast<float2*>(out + r * F_DIM + lane * 2) = o;
}

extern "C" void kernel_launch(void* const* d_in, const int* in_sizes, int n_in,
                              void* d_out, int out_size, void* d_ws, size_t ws_size,
                              hipStream_t stream) {
    const float* x      = (const float*)d_in[0];
    const float* weight = (const float*)d_in[1];
    const float* bias   = (const float*)d_in[2];
    const float* evals  = (const float*)d_in[3];
    const int*   erows  = (const int*)d_in[4];
    const int*   ecols  = (const int*)d_in[5];
    float* out = (float*)d_out;

    const int n_nodes = in_sizes[0] / F_DIM;   // 50000
    const int n_edges = in_sizes[3];           // 625000

    const int scan_blocks = (n_nodes + SCAN_PER_BLOCK - 1) / SCAN_PER_BLOCK;  // 49

    // Workspace layout (~31.2 MB)
    float* support = (float*)d_ws;                                // n_nodes*128 f32
    int*   cnt     = (int*)(support + (size_t)n_nodes * F_DIM);   // n_nodes
    int*   off     = cnt + n_nodes;                               // n_nodes+1
    int*   cur     = off + n_nodes + 1;                           // n_nodes
    int*   bsum    = cur + n_nodes;                               // scan_blocks
    int*   bbase   = bsum + SCAN_T;                               // scan_blocks
    int*   scol    = bbase + SCAN_T;                              // n_edges
    float* sval    = (float*)(scol + n_edges);                    // n_edges

    // 1) zero the histogram
    hipMemsetAsync(cnt, 0, n_nodes * sizeof(int), stream);

    // 2) support = x @ W
    int gemm_blocks = (n_nodes + ROWS_PER_BLOCK - 1) / ROWS_PER_BLOCK;
    gemm_kernel<<<gemm_blocks, 256, 0, stream>>>(x, weight, support, n_nodes);

    // 3) counting sort by row (hist -> 3-phase scan -> scatter)
    hist_kernel<<<1024, 256, 0, stream>>>(erows, cnt, n_edges);
    scan_phase1<<<scan_blocks, SCAN_T, 0, stream>>>(cnt, bsum, n_nodes);
    scan_phase2<<<1, SCAN_T, 0, stream>>>(bsum, bbase, off, scan_blocks, n_nodes);
    scan_phase3<<<scan_blocks, SCAN_T, 0, stream>>>(cnt, bbase, off, cur, n_nodes);
    scatter_kernel<<<1024, 256, 0, stream>>>(erows, ecols, evals, cur, scol, sval, n_edges);

    // 4) out[r] = sum_e v*support[col] + bias   (wave per row, no atomics)
    int blocks = (n_nodes * 64 + 255) / 256;
    spmm_csr_kernel<<<blocks, 256, 0, stream>>>(support, off, scol, sval, bias, out, n_nodes);
}

// Round 4
// 154.851 us; speedup vs baseline: 7.1754x; 1.3279x over previous
//
#include <hip/hip_runtime.h>
#include <hip/hip_bf16.h>

// GCN layer: out = spmm(adj, x @ W) + bias
// Inputs: x[50000,128] f32, weight[128,128] f32, bias[128] f32,
//         edge_vals[625000] f32, edge_rows[625000] i32, edge_cols[625000] i32
// Output: out[50000,128] f32
//
// Round 4 strategy:
//  - support kept in bf16 (halves spmm gather bytes; 12.8 MB L2 footprint)
//  - GEMM via mfma_f32_16x16x32_bf16 (w pre-transposed to bf16)
//  - counting-sort edges to CSR; (col,val) packed into 8-B int2
//  - pull spmm: wave per row, 4 edges in flight (16 lanes x 16 B each)

#define F_DIM 128

#define SCAN_T 256
#define SCAN_ITEMS 4
#define SCAN_PER_BLOCK (SCAN_T * SCAN_ITEMS)   // 1024 elements per block

typedef short bf16x8 __attribute__((ext_vector_type(8)));
typedef float f32x4 __attribute__((ext_vector_type(4)));

__device__ __forceinline__ unsigned short f2bf(float f) {
    unsigned int u = __float_as_uint(f);
    u += 0x7FFFu + ((u >> 16) & 1u);   // round-to-nearest-even
    return (unsigned short)(u >> 16);
}

// ---------------- wt[n][k] = bf16(w[k][n]) ----------------
__global__ void __launch_bounds__(256)
wconv_kernel(const float* __restrict__ w, unsigned short* __restrict__ wt) {
    int idx = blockIdx.x * blockDim.x + threadIdx.x;
    int n = idx >> 7, k = idx & 127;
    wt[n * F_DIM + k] = f2bf(w[k * F_DIM + n]);
}

// ---------------- GEMM: support_bf16 = bf16(x @ W) via MFMA ----------------
// Block = 256 = 4 waves. Block tile: 16 rows x 64 cols (wave: 16x16).
// grid = (50000/16) * 2; bid>>1 = row-tile, bid&1 = col-half.
__global__ void __launch_bounds__(256)
gemm_mfma_kernel(const float* __restrict__ x, const unsigned short* __restrict__ wt,
                 unsigned short* __restrict__ support) {
    const int tid = threadIdx.x;
    const int wid = tid >> 6;
    const int lane = tid & 63;
    const int l15 = lane & 15;
    const int lhi = lane >> 4;           // 0..3

    const int m0 = (blockIdx.x >> 1) * 16;           // 3125*16 = 50000 exact
    const int n0 = (blockIdx.x & 1) * 64 + wid * 16;

    // A: x[m0 + l15][8*lhi + j + k0]   (f32 -> bf16 in-kernel)
    // B: wt[n0 + l15][8*lhi + j + k0]  (= w[k][n] transposed, bf16)
    const float* xrow = x + (size_t)(m0 + l15) * F_DIM + lhi * 8;
    const unsigned short* wrow = wt + (size_t)(n0 + l15) * F_DIM + lhi * 8;

    f32x4 acc = {0.f, 0.f, 0.f, 0.f};
#pragma unroll
    for (int k0 = 0; k0 < F_DIM; k0 += 32) {
        float4 xa = *reinterpret_cast<const float4*>(xrow + k0);
        float4 xb = *reinterpret_cast<const float4*>(xrow + k0 + 4);
        bf16x8 a, b;
        a[0] = (short)f2bf(xa.x); a[1] = (short)f2bf(xa.y);
        a[2] = (short)f2bf(xa.z); a[3] = (short)f2bf(xa.w);
        a[4] = (short)f2bf(xb.x); a[5] = (short)f2bf(xb.y);
        a[6] = (short)f2bf(xb.z); a[7] = (short)f2bf(xb.w);
        b = *reinterpret_cast<const bf16x8*>(wrow + k0);
        acc = __builtin_amdgcn_mfma_f32_16x16x32_bf16(a, b, acc, 0, 0, 0);
    }

    // D: row = m0 + 4*lhi + i, col = n0 + l15
    unsigned short* sp = support + (size_t)(m0 + 4 * lhi) * F_DIM + n0 + l15;
#pragma unroll
    for (int i = 0; i < 4; i++)
        sp[(size_t)i * F_DIM] = f2bf(acc[i]);
}

// ---------------- Counting sort: histogram ----------------
__global__ void hist_kernel(const int* __restrict__ rows, int* __restrict__ cnt,
                            int n_edges) {
    int idx = blockIdx.x * blockDim.x + threadIdx.x;
    int stride = gridDim.x * blockDim.x;
    for (int e = idx; e < n_edges; e += stride)
        atomicAdd(&cnt[rows[e]], 1);
}

// ---------------- Scan phase 1: per-block sums ----------------
__global__ void __launch_bounds__(SCAN_T)
scan_phase1(const int* __restrict__ cnt, int* __restrict__ bsum, int n) {
    __shared__ int red[SCAN_T];
    const int t = threadIdx.x;
    const int base = blockIdx.x * SCAN_PER_BLOCK + t * SCAN_ITEMS;

    int s = 0;
#pragma unroll
    for (int j = 0; j < SCAN_ITEMS; j++) {
        int i = base + j;
        if (i < n) s += cnt[i];
    }
    red[t] = s;
    __syncthreads();
    for (int d = SCAN_T / 2; d > 0; d >>= 1) {
        if (t < d) red[t] += red[t + d];
        __syncthreads();
    }
    if (t == 0) bsum[blockIdx.x] = red[0];
}

// ---------------- Scan phase 2: scan the block sums (1 small block) -------
__global__ void __launch_bounds__(SCAN_T)
scan_phase2(const int* __restrict__ bsum, int* __restrict__ bbase,
            int* __restrict__ off, int nblocks, int n) {
    __shared__ int sh[SCAN_T];
    const int t = threadIdx.x;
    int v = (t < nblocks) ? bsum[t] : 0;
    sh[t] = v;
    __syncthreads();
    for (int d = 1; d < SCAN_T; d <<= 1) {
        int u = (t >= d) ? sh[t - d] : 0;
        __syncthreads();
        sh[t] += u;
        __syncthreads();
    }
    if (t < nblocks) bbase[t] = (t == 0) ? 0 : sh[t - 1];
    if (t == 0) off[n] = sh[SCAN_T - 1];   // grand total (= n_edges)
}

// ---------------- Scan phase 3: emit per-element offsets ----------------
__global__ void __launch_bounds__(SCAN_T)
scan_phase3(const int* __restrict__ cnt, const int* __restrict__ bbase,
            int* __restrict__ off, int* __restrict__ cur, int n) {
    __shared__ int sh[SCAN_T];
    const int t = threadIdx.x;
    const int base = blockIdx.x * SCAN_PER_BLOCK + t * SCAN_ITEMS;

    int local[SCAN_ITEMS];
    int s = 0;
#pragma unroll
    for (int j = 0; j < SCAN_ITEMS; j++) {
        int i = base + j;
        local[j] = (i < n) ? cnt[i] : 0;
        s += local[j];
    }
    sh[t] = s;
    __syncthreads();
    for (int d = 1; d < SCAN_T; d <<= 1) {
        int u = (t >= d) ? sh[t - d] : 0;
        __syncthreads();
        sh[t] += u;
        __syncthreads();
    }
    int run = bbase[blockIdx.x] + ((t == 0) ? 0 : sh[t - 1]);
#pragma unroll
    for (int j = 0; j < SCAN_ITEMS; j++) {
        int i = base + j;
        if (i < n) {
            off[i] = run;
            cur[i] = run;
            run += local[j];
        }
    }
}

// ---------------- Scatter edges into CSR order, packing (col,val) --------
__global__ void scatter_kernel(const int* __restrict__ rows,
                               const int* __restrict__ cols,
                               const float* __restrict__ vals,
                               int* __restrict__ cur,
                               int2* __restrict__ epack, int n_edges) {
    int idx = blockIdx.x * blockDim.x + threadIdx.x;
    int stride = gridDim.x * blockDim.x;
    for (int e = idx; e < n_edges; e += stride) {
        int pos = atomicAdd(&cur[rows[e]], 1);
        epack[pos] = make_int2(cols[e], __float_as_int(vals[e]));
    }
}

// ---------------- SpMM over CSR: wave per row, 4 edges in flight ----------
__global__ void __launch_bounds__(256)
spmm_csr_kernel(const unsigned short* __restrict__ support,
                const int* __restrict__ off, const int2* __restrict__ epack,
                const float* __restrict__ bias, float* __restrict__ out,
                int n_nodes) {
    const int wave = (blockIdx.x * blockDim.x + threadIdx.x) >> 6;
    if (wave >= n_nodes) return;
    const int lane = threadIdx.x & 63;
    const int q = lane >> 4;      // edge slot 0..3
    const int sub = lane & 15;    // covers cols sub*8 .. sub*8+7

    const int r = wave;
    const int s = off[r];
    const int e = off[r + 1];

    float acc[8] = {0.f, 0.f, 0.f, 0.f, 0.f, 0.f, 0.f, 0.f};
    for (int i = s + q; i < e; i += 4) {
        int2 p = epack[i];
        float v = __int_as_float(p.y);
        uint4 sv = *reinterpret_cast<const uint4*>(support + (size_t)p.x * F_DIM + sub * 8);
        acc[0] += v * __uint_as_float(sv.x << 16);
        acc[1] += v * __uint_as_float(sv.x & 0xFFFF0000u);
        acc[2] += v * __uint_as_float(sv.y << 16);
        acc[3] += v * __uint_as_float(sv.y & 0xFFFF0000u);
        acc[4] += v * __uint_as_float(sv.z << 16);
        acc[5] += v * __uint_as_float(sv.z & 0xFFFF0000u);
        acc[6] += v * __uint_as_float(sv.w << 16);
        acc[7] += v * __uint_as_float(sv.w & 0xFFFF0000u);
    }

    // reduce the 4 edge slots
#pragma unroll
    for (int j = 0; j < 8; j++) {
        acc[j] += __shfl_xor(acc[j], 16);
        acc[j] += __shfl_xor(acc[j], 32);
    }

    if (q == 0) {
        float4 b0 = *reinterpret_cast<const float4*>(bias + sub * 8);
        float4 b1 = *reinterpret_cast<const float4*>(bias + sub * 8 + 4);
        float4 o0 = make_float4(acc[0] + b0.x, acc[1] + b0.y, acc[2] + b0.z, acc[3] + b0.w);
        float4 o1 = make_float4(acc[4] + b1.x, acc[5] + b1.y, acc[6] + b1.z, acc[7] + b1.w);
        float4* op = reinterpret_cast<float4*>(out + (size_t)r * F_DIM + sub * 8);
        op[0] = o0;
        op[1] = o1;
    }
}

extern "C" void kernel_launch(void* const* d_in, const int* in_sizes, int n_in,
                              void* d_out, int out_size, void* d_ws, size_t ws_size,
                              hipStream_t stream) {
    const float* x      = (const float*)d_in[0];
    const float* weight = (const float*)d_in[1];
    const float* bias   = (const float*)d_in[2];
    const float* evals  = (const float*)d_in[3];
    const int*   erows  = (const int*)d_in[4];
    const int*   ecols  = (const int*)d_in[5];
    float* out = (float*)d_out;

    const int n_nodes = in_sizes[0] / F_DIM;   // 50000
    const int n_edges = in_sizes[3];           // 625000

    const int scan_blocks = (n_nodes + SCAN_PER_BLOCK - 1) / SCAN_PER_BLOCK;  // 49

    // Workspace layout (~18.5 MB)
    unsigned short* support = (unsigned short*)d_ws;                  // n_nodes*128 bf16
    unsigned short* wt      = support + (size_t)n_nodes * F_DIM;      // 128*128 bf16
    int* cnt   = (int*)(wt + F_DIM * F_DIM);                          // n_nodes
    int* off   = cnt + n_nodes;                                       // n_nodes+1
    int* cur   = off + n_nodes + 1;                                   // n_nodes
    int* bsum  = cur + n_nodes;                                       // SCAN_T
    int* bbase = bsum + SCAN_T;                                       // SCAN_T
    uintptr_t ep = (uintptr_t)(bbase + SCAN_T);
    ep = (ep + 15) & ~(uintptr_t)15;
    int2* epack = (int2*)ep;                                          // n_edges * 8B

    // 1) zero the histogram
    hipMemsetAsync(cnt, 0, n_nodes * sizeof(int), stream);

    // 2) wt = bf16(w^T); support = bf16(x @ W) via MFMA
    wconv_kernel<<<(F_DIM * F_DIM) / 256, 256, 0, stream>>>(weight, wt);
    gemm_mfma_kernel<<<(n_nodes / 16) * 2, 256, 0, stream>>>(x, wt, support);

    // 3) counting sort by row (hist -> 3-phase scan -> scatter, packed)
    hist_kernel<<<1024, 256, 0, stream>>>(erows, cnt, n_edges);
    scan_phase1<<<scan_blocks, SCAN_T, 0, stream>>>(cnt, bsum, n_nodes);
    scan_phase2<<<1, SCAN_T, 0, stream>>>(bsum, bbase, off, scan_blocks, n_nodes);
    scan_phase3<<<scan_blocks, SCAN_T, 0, stream>>>(cnt, bbase, off, cur, n_nodes);
    scatter_kernel<<<1024, 256, 0, stream>>>(erows, ecols, evals, cur, epack, n_edges);

    // 4) out[r] = sum_e v*support[col] + bias   (wave per row, no atomics)
    int blocks = (n_nodes * 64 + 255) / 256;
    spmm_csr_kernel<<<blocks, 256, 0, stream>>>(support, off, epack, bias, out, n_nodes);
}

// Round 5
// 151.744 us; speedup vs baseline: 7.3223x; 1.0205x over previous
//
#include <hip/hip_runtime.h>
#include <hip/hip_bf16.h>

// GCN layer: out = spmm(adj, x @ W) + bias
// Inputs: x[50000,128] f32, weight[128,128] f32, bias[128] f32,
//         edge_vals[625000] f32, edge_rows[625000] i32, edge_cols[625000] i32
// Output: out[50000,128] f32
//
// Round 5:
//  - scatter & hist: one edge per thread (latency hiding via TLP; round-4
//    scatter was 44 us at 30% occupancy with serialized atomic round-trips)
//  - wconv folded into hist launch (one fewer dispatch)
//  - spmm: prefetch next edge record over the 256-B gather

#define F_DIM 128

#define SCAN_T 256
#define SCAN_ITEMS 4
#define SCAN_PER_BLOCK (SCAN_T * SCAN_ITEMS)   // 1024 elements per block

typedef short bf16x8 __attribute__((ext_vector_type(8)));
typedef float f32x4 __attribute__((ext_vector_type(4)));

__device__ __forceinline__ unsigned short f2bf(float f) {
    unsigned int u = __float_as_uint(f);
    u += 0x7FFFu + ((u >> 16) & 1u);   // round-to-nearest-even
    return (unsigned short)(u >> 16);
}

// ------------- hist (1 edge/thread) + wconv folded in (last 64 blocks) ----
__global__ void __launch_bounds__(256)
histw_kernel(const int* __restrict__ rows, int* __restrict__ cnt, int n_edges,
             const float* __restrict__ w, unsigned short* __restrict__ wt,
             int hist_blocks) {
    if ((int)blockIdx.x >= hist_blocks) {
        // wt[n][k] = bf16(w[k][n]) ; 16384 elements over 64 blocks
        int idx = (blockIdx.x - hist_blocks) * 256 + threadIdx.x;
        int n = idx >> 7, k = idx & 127;
        wt[n * F_DIM + k] = f2bf(w[k * F_DIM + n]);
        return;
    }
    int e = blockIdx.x * blockDim.x + threadIdx.x;
    if (e < n_edges) atomicAdd(&cnt[rows[e]], 1);
}

// ---------------- GEMM: support_bf16 = bf16(x @ W) via MFMA ----------------
// Block = 256 = 4 waves. Block tile: 16 rows x 64 cols (wave: 16x16).
__global__ void __launch_bounds__(256)
gemm_mfma_kernel(const float* __restrict__ x, const unsigned short* __restrict__ wt,
                 unsigned short* __restrict__ support) {
    const int tid = threadIdx.x;
    const int wid = tid >> 6;
    const int lane = tid & 63;
    const int l15 = lane & 15;
    const int lhi = lane >> 4;           // 0..3

    const int m0 = (blockIdx.x >> 1) * 16;           // 3125*16 = 50000 exact
    const int n0 = (blockIdx.x & 1) * 64 + wid * 16;

    const float* xrow = x + (size_t)(m0 + l15) * F_DIM + lhi * 8;
    const unsigned short* wrow = wt + (size_t)(n0 + l15) * F_DIM + lhi * 8;

    f32x4 acc = {0.f, 0.f, 0.f, 0.f};
#pragma unroll
    for (int k0 = 0; k0 < F_DIM; k0 += 32) {
        float4 xa = *reinterpret_cast<const float4*>(xrow + k0);
        float4 xb = *reinterpret_cast<const float4*>(xrow + k0 + 4);
        bf16x8 a, b;
        a[0] = (short)f2bf(xa.x); a[1] = (short)f2bf(xa.y);
        a[2] = (short)f2bf(xa.z); a[3] = (short)f2bf(xa.w);
        a[4] = (short)f2bf(xb.x); a[5] = (short)f2bf(xb.y);
        a[6] = (short)f2bf(xb.z); a[7] = (short)f2bf(xb.w);
        b = *reinterpret_cast<const bf16x8*>(wrow + k0);
        acc = __builtin_amdgcn_mfma_f32_16x16x32_bf16(a, b, acc, 0, 0, 0);
    }

    // D: row = m0 + 4*lhi + i, col = n0 + l15
    unsigned short* sp = support + (size_t)(m0 + 4 * lhi) * F_DIM + n0 + l15;
#pragma unroll
    for (int i = 0; i < 4; i++)
        sp[(size_t)i * F_DIM] = f2bf(acc[i]);
}

// ---------------- Scan phase 1: per-block sums ----------------
__global__ void __launch_bounds__(SCAN_T)
scan_phase1(const int* __restrict__ cnt, int* __restrict__ bsum, int n) {
    __shared__ int red[SCAN_T];
    const int t = threadIdx.x;
    const int base = blockIdx.x * SCAN_PER_BLOCK + t * SCAN_ITEMS;

    int s = 0;
#pragma unroll
    for (int j = 0; j < SCAN_ITEMS; j++) {
        int i = base + j;
        if (i < n) s += cnt[i];
    }
    red[t] = s;
    __syncthreads();
    for (int d = SCAN_T / 2; d > 0; d >>= 1) {
        if (t < d) red[t] += red[t + d];
        __syncthreads();
    }
    if (t == 0) bsum[blockIdx.x] = red[0];
}

// ---------------- Scan phase 2: scan the block sums (1 small block) -------
__global__ void __launch_bounds__(SCAN_T)
scan_phase2(const int* __restrict__ bsum, int* __restrict__ bbase,
            int* __restrict__ off, int nblocks, int n) {
    __shared__ int sh[SCAN_T];
    const int t = threadIdx.x;
    int v = (t < nblocks) ? bsum[t] : 0;
    sh[t] = v;
    __syncthreads();
    for (int d = 1; d < SCAN_T; d <<= 1) {
        int u = (t >= d) ? sh[t - d] : 0;
        __syncthreads();
        sh[t] += u;
        __syncthreads();
    }
    if (t < nblocks) bbase[t] = (t == 0) ? 0 : sh[t - 1];
    if (t == 0) off[n] = sh[SCAN_T - 1];   // grand total (= n_edges)
}

// ---------------- Scan phase 3: emit per-element offsets ----------------
__global__ void __launch_bounds__(SCAN_T)
scan_phase3(const int* __restrict__ cnt, const int* __restrict__ bbase,
            int* __restrict__ off, int* __restrict__ cur, int n) {
    __shared__ int sh[SCAN_T];
    const int t = threadIdx.x;
    const int base = blockIdx.x * SCAN_PER_BLOCK + t * SCAN_ITEMS;

    int local[SCAN_ITEMS];
    int s = 0;
#pragma unroll
    for (int j = 0; j < SCAN_ITEMS; j++) {
        int i = base + j;
        local[j] = (i < n) ? cnt[i] : 0;
        s += local[j];
    }
    sh[t] = s;
    __syncthreads();
    for (int d = 1; d < SCAN_T; d <<= 1) {
        int u = (t >= d) ? sh[t - d] : 0;
        __syncthreads();
        sh[t] += u;
        __syncthreads();
    }
    int run = bbase[blockIdx.x] + ((t == 0) ? 0 : sh[t - 1]);
#pragma unroll
    for (int j = 0; j < SCAN_ITEMS; j++) {
        int i = base + j;
        if (i < n) {
            off[i] = run;
            cur[i] = run;
            run += local[j];
        }
    }
}

// -------- Scatter edges into CSR order (1 edge/thread), packed (col,val) --
__global__ void __launch_bounds__(256)
scatter_kernel(const int* __restrict__ rows, const int* __restrict__ cols,
               const float* __restrict__ vals, int* __restrict__ cur,
               int2* __restrict__ epack, int n_edges) {
    int e = blockIdx.x * blockDim.x + threadIdx.x;
    if (e >= n_edges) return;
    int r = rows[e];
    int c = cols[e];
    float v = vals[e];
    int pos = atomicAdd(&cur[r], 1);
    epack[pos] = make_int2(c, __float_as_int(v));
}

// ---------------- SpMM over CSR: wave per row, 4 edges in flight ----------
__global__ void __launch_bounds__(256)
spmm_csr_kernel(const unsigned short* __restrict__ support,
                const int* __restrict__ off, const int2* __restrict__ epack,
                const float* __restrict__ bias, float* __restrict__ out,
                int n_nodes) {
    const int wave = (blockIdx.x * blockDim.x + threadIdx.x) >> 6;
    if (wave >= n_nodes) return;
    const int lane = threadIdx.x & 63;
    const int q = lane >> 4;      // edge slot 0..3
    const int sub = lane & 15;    // covers cols sub*8 .. sub*8+7

    const int r = wave;
    const int s = off[r];
    const int e = off[r + 1];

    float acc[8] = {0.f, 0.f, 0.f, 0.f, 0.f, 0.f, 0.f, 0.f};

    int i = s + q;
    if (i < e) {
        int2 p = epack[i];
        while (true) {
            const int inext = i + 4;
            const bool more = inext < e;
            int2 pn;
            if (more) pn = epack[inext];          // prefetch over the gather
            float v = __int_as_float(p.y);
            uint4 sv = *reinterpret_cast<const uint4*>(
                support + (size_t)p.x * F_DIM + sub * 8);
            acc[0] += v * __uint_as_float(sv.x << 16);
            acc[1] += v * __uint_as_float(sv.x & 0xFFFF0000u);
            acc[2] += v * __uint_as_float(sv.y << 16);
            acc[3] += v * __uint_as_float(sv.y & 0xFFFF0000u);
            acc[4] += v * __uint_as_float(sv.z << 16);
            acc[5] += v * __uint_as_float(sv.z & 0xFFFF0000u);
            acc[6] += v * __uint_as_float(sv.w << 16);
            acc[7] += v * __uint_as_float(sv.w & 0xFFFF0000u);
            if (!more) break;
            i = inext;
            p = pn;
        }
    }

    // reduce the 4 edge slots
#pragma unroll
    for (int j = 0; j < 8; j++) {
        acc[j] += __shfl_xor(acc[j], 16);
        acc[j] += __shfl_xor(acc[j], 32);
    }

    if (q == 0) {
        float4 b0 = *reinterpret_cast<const float4*>(bias + sub * 8);
        float4 b1 = *reinterpret_cast<const float4*>(bias + sub * 8 + 4);
        float4 o0 = make_float4(acc[0] + b0.x, acc[1] + b0.y, acc[2] + b0.z, acc[3] + b0.w);
        float4 o1 = make_float4(acc[4] + b1.x, acc[5] + b1.y, acc[6] + b1.z, acc[7] + b1.w);
        float4* op = reinterpret_cast<float4*>(out + (size_t)r * F_DIM + sub * 8);
        op[0] = o0;
        op[1] = o1;
    }
}

extern "C" void kernel_launch(void* const* d_in, const int* in_sizes, int n_in,
                              void* d_out, int out_size, void* d_ws, size_t ws_size,
                              hipStream_t stream) {
    const float* x      = (const float*)d_in[0];
    const float* weight = (const float*)d_in[1];
    const float* bias   = (const float*)d_in[2];
    const float* evals  = (const float*)d_in[3];
    const int*   erows  = (const int*)d_in[4];
    const int*   ecols  = (const int*)d_in[5];
    float* out = (float*)d_out;

    const int n_nodes = in_sizes[0] / F_DIM;   // 50000
    const int n_edges = in_sizes[3];           // 625000

    const int scan_blocks = (n_nodes + SCAN_PER_BLOCK - 1) / SCAN_PER_BLOCK;  // 49
    const int edge_blocks = (n_edges + 255) / 256;                            // 2442

    // Workspace layout (~18.5 MB)
    unsigned short* support = (unsigned short*)d_ws;                  // n_nodes*128 bf16
    unsigned short* wt      = support + (size_t)n_nodes * F_DIM;      // 128*128 bf16
    int* cnt   = (int*)(wt + F_DIM * F_DIM);                          // n_nodes
    int* off   = cnt + n_nodes;                                       // n_nodes+1
    int* cur   = off + n_nodes + 1;                                   // n_nodes
    int* bsum  = cur + n_nodes;                                       // SCAN_T
    int* bbase = bsum + SCAN_T;                                       // SCAN_T
    uintptr_t ep = (uintptr_t)(bbase + SCAN_T);
    ep = (ep + 15) & ~(uintptr_t)15;
    int2* epack = (int2*)ep;                                          // n_edges * 8B

    // 1) zero the histogram
    hipMemsetAsync(cnt, 0, n_nodes * sizeof(int), stream);

    // 2) hist (1 edge/thread) + wconv piggyback
    histw_kernel<<<edge_blocks + 64, 256, 0, stream>>>(erows, cnt, n_edges,
                                                       weight, wt, edge_blocks);

    // 3) support = bf16(x @ W) via MFMA
    gemm_mfma_kernel<<<(n_nodes / 16) * 2, 256, 0, stream>>>(x, wt, support);

    // 4) 3-phase scan + scatter (1 edge/thread)
    scan_phase1<<<scan_blocks, SCAN_T, 0, stream>>>(cnt, bsum, n_nodes);
    scan_phase2<<<1, SCAN_T, 0, stream>>>(bsum, bbase, off, scan_blocks, n_nodes);
    scan_phase3<<<scan_blocks, SCAN_T, 0, stream>>>(cnt, bbase, off, cur, n_nodes);
    scatter_kernel<<<edge_blocks, 256, 0, stream>>>(erows, ecols, evals, cur, epack, n_edges);

    // 5) out[r] = sum_e v*support[col] + bias   (wave per row, no atomics)
    int blocks = (n_nodes * 64 + 255) / 256;
    spmm_csr_kernel<<<blocks, 256, 0, stream>>>(support, off, epack, bias, out, n_nodes);
}